// Round 1
// baseline (1211.763 us; speedup 1.0000x reference)
//
#include <hip/hip_runtime.h>
#include <hip/hip_bf16.h>
#include <math.h>

#define N0c 120000
#define N1c 20000
#define N2c 6000
#define N3c 1600
#define Bc  64
#define E1c 480000
#define E2c 144000
#define E3c 38400

__device__ __forceinline__ float eluf(float x) {
    return x > 0.0f ? x : expm1f(x);
}

// monotone float -> uint mapping for atomicMax-based segment max
__device__ __forceinline__ unsigned f2sort(float f) {
    unsigned u = __float_as_uint(f);
    return (u & 0x80000000u) ? ~u : (u | 0x80000000u);
}
__device__ __forceinline__ float sort2f(unsigned u) {
    unsigned bits = (u & 0x80000000u) ? (u & 0x7FFFFFFFu) : ~u;
    return __uint_as_float(bits);
}

__global__ void segmax_scatter(const float* __restrict__ x, const int* __restrict__ cl,
                               unsigned* __restrict__ buf, int total, int shiftC) {
    int idx = blockIdx.x * blockDim.x + threadIdx.x;
    if (idx >= total) return;
    int n = idx >> shiftC;
    int c = idx - (n << shiftC);
    atomicMax(&buf[(cl[n] << shiftC) + c], f2sort(x[idx]));
}

__global__ void segmax_decode(unsigned* __restrict__ buf, int total) {
    int idx = blockIdx.x * blockDim.x + threadIdx.x;
    if (idx >= total) return;
    float f = sort2f(buf[idx]);
    unsigned b = __float_as_uint(f);
    if ((b & 0x7F800000u) == 0x7F800000u) f = 0.0f;   // !isfinite -> 0
    ((float*)buf)[idx] = f;
}

__device__ __forceinline__ void compute_basis(const float* __restrict__ pseudo, int e,
                                              float basis[8], int kidx[8]) {
    float f[3];
    int loi[3];
    #pragma unroll
    for (int d = 0; d < 3; d++) {
        float p = pseudo[e * 3 + d] * 4.0f;
        float l = floorf(p);
        l = fminf(fmaxf(l, 0.0f), 3.0f);
        f[d] = p - l;
        loi[d] = (int)l;
    }
    #pragma unroll
    for (int s = 0; s < 8; s++) {
        int b0 = s & 1, b1 = (s >> 1) & 1, b2 = (s >> 2) & 1;
        float w0 = b0 ? f[0] : 1.0f - f[0];
        float w1 = b1 ? f[1] : 1.0f - f[1];
        float w2 = b2 ? f[2] : 1.0f - f[2];
        basis[s] = w0 * w1 * w2;
        kidx[s] = (loi[0] + b0) + 5 * (loi[1] + b1) + 25 * (loi[2] + b2);
    }
}

// conv1: C_in = 1, C_out = 64. One wave per edge, lane = out channel.
__global__ void conv1_edge(const int* __restrict__ edge, const float* __restrict__ pseudo,
                           const float* __restrict__ W, const float* __restrict__ x,
                           float* __restrict__ agg, float* __restrict__ deg) {
    int t = blockIdx.x * blockDim.x + threadIdx.x;
    int e = t >> 6;
    int lane = t & 63;
    if (e >= E1c) return;
    int src = edge[e], dst = edge[E1c + e];
    float basis[8]; int kidx[8];
    compute_basis(pseudo, e, basis, kidx);
    float acc = 0.0f;
    #pragma unroll
    for (int s = 0; s < 8; s++)
        acc = fmaf(basis[s], W[(kidx[s] << 6) + lane], acc);
    float val = x[src] * acc;
    atomicAdd(&agg[(dst << 6) + lane], val);
    if (lane == 0) atomicAdd(&deg[dst], 1.0f);
}

// conv2: C_in = 64, C_out = 64. One wave per edge, lane = out channel.
__global__ void conv2_edge(const int* __restrict__ edge, const float* __restrict__ pseudo,
                           const float* __restrict__ W, const float* __restrict__ x,
                           float* __restrict__ agg, float* __restrict__ deg, int E) {
    __shared__ float xs[4][64];
    int lane = threadIdx.x & 63;
    int wslot = threadIdx.x >> 6;
    int e = (blockIdx.x << 2) + wslot;
    bool active = e < E;
    int src = 0, dst = 0;
    float basis[8]; int kidx[8];
    float xv = 0.0f;
    if (active) {
        src = edge[e]; dst = edge[E + e];
        compute_basis(pseudo, e, basis, kidx);
        xv = x[(src << 6) + lane];
    }
    xs[wslot][lane] = xv;
    __syncthreads();
    if (!active) return;
    const float* xrow = xs[wslot];
    float acc = 0.0f;
    #pragma unroll 2
    for (int i = 0; i < 64; i += 4) {
        float4 xq = *((const float4*)(xrow + i));
        #pragma unroll
        for (int j = 0; j < 4; j++) {
            float xi = (&xq.x)[j];
            const float* Wi = W + ((i + j) << 6) + lane;
            float tt = 0.0f;
            #pragma unroll
            for (int s = 0; s < 8; s++)
                tt = fmaf(basis[s], Wi[kidx[s] << 12], tt);
            acc = fmaf(xi, tt, acc);
        }
    }
    atomicAdd(&agg[(dst << 6) + lane], acc);
    if (lane == 0) atomicAdd(&deg[dst], 1.0f);
}

// conv3: C_in = 64, C_out = 128. One wave per edge, lane handles o and o+64.
__global__ void conv3_edge(const int* __restrict__ edge, const float* __restrict__ pseudo,
                           const float* __restrict__ W, const float* __restrict__ x,
                           float* __restrict__ agg, float* __restrict__ deg, int E) {
    __shared__ float xs[4][64];
    int lane = threadIdx.x & 63;
    int wslot = threadIdx.x >> 6;
    int e = (blockIdx.x << 2) + wslot;
    bool active = e < E;
    int src = 0, dst = 0;
    float basis[8]; int kidx[8];
    float xv = 0.0f;
    if (active) {
        src = edge[e]; dst = edge[E + e];
        compute_basis(pseudo, e, basis, kidx);
        xv = x[(src << 6) + lane];
    }
    xs[wslot][lane] = xv;
    __syncthreads();
    if (!active) return;
    const float* xrow = xs[wslot];
    float acc0 = 0.0f, acc1 = 0.0f;
    #pragma unroll 2
    for (int i = 0; i < 64; i += 4) {
        float4 xq = *((const float4*)(xrow + i));
        #pragma unroll
        for (int j = 0; j < 4; j++) {
            float xi = (&xq.x)[j];
            const float* Wi = W + ((i + j) << 7);
            float t0 = 0.0f, t1 = 0.0f;
            #pragma unroll
            for (int s = 0; s < 8; s++) {
                const float* Wk = Wi + (kidx[s] << 13);
                t0 = fmaf(basis[s], Wk[lane], t0);
                t1 = fmaf(basis[s], Wk[lane + 64], t1);
            }
            acc0 = fmaf(xi, t0, acc0);
            acc1 = fmaf(xi, t1, acc1);
        }
    }
    atomicAdd(&agg[(dst << 7) + lane], acc0);
    atomicAdd(&agg[(dst << 7) + 64 + lane], acc1);
    if (lane == 0) atomicAdd(&deg[dst], 1.0f);
}

// node update for conv1 (C_in = 1): out = elu(agg/deg + x*root + b)
__global__ void node1(const float* __restrict__ agg, const float* __restrict__ deg,
                      const float* __restrict__ xm, const float* __restrict__ root,
                      const float* __restrict__ b, float* __restrict__ out, int n_nodes) {
    int idx = blockIdx.x * blockDim.x + threadIdx.x;
    if (idx >= n_nodes * 64) return;
    int v = idx >> 6, o = idx & 63;
    float d = fmaxf(deg[v], 1.0f);
    out[idx] = eluf(agg[idx] / d + xm[v] * root[o] + b[o]);
}

// node update with 64 x COUT root matmul
template <int COUT>
__global__ void node_mm(const float* __restrict__ agg, const float* __restrict__ deg,
                        const float* __restrict__ xm, const float* __restrict__ root,
                        const float* __restrict__ b, float* __restrict__ out, int n_nodes) {
    int idx = blockIdx.x * blockDim.x + threadIdx.x;
    if (idx >= n_nodes * COUT) return;
    int v = idx / COUT, o = idx % COUT;
    const float* xr = xm + v * 64;
    float s = 0.0f;
    #pragma unroll 8
    for (int i = 0; i < 64; i++)
        s = fmaf(xr[i], root[i * COUT + o], s);
    float d = fmaxf(deg[v], 1.0f);
    out[idx] = eluf(agg[idx] / d + s + b[o]);
}

__global__ void fc1_k(const float* __restrict__ xin, const float* __restrict__ w,
                      const float* __restrict__ b, float* __restrict__ h) {
    __shared__ float xsh[1024];
    int row = blockIdx.x;
    for (int i = threadIdx.x; i < 1024; i += 256) xsh[i] = xin[row * 1024 + i];
    __syncthreads();
    int o = threadIdx.x;
    float acc = b[o];
    #pragma unroll 8
    for (int i = 0; i < 1024; i++) acc = fmaf(xsh[i], w[i * 256 + o], acc);
    h[row * 256 + o] = eluf(acc);
}

__global__ void fc2_k(const float* __restrict__ h, const float* __restrict__ w,
                      const float* __restrict__ b, float* __restrict__ out) {
    __shared__ float hs[256];
    __shared__ float lg[10];
    int row = blockIdx.x;
    int t = threadIdx.x;
    for (int i = t; i < 256; i += 64) hs[i] = h[row * 256 + i];
    __syncthreads();
    if (t < 10) {
        float acc = b[t];
        for (int i = 0; i < 256; i++) acc = fmaf(hs[i], w[i * 10 + t], acc);
        lg[t] = acc;
    }
    __syncthreads();
    if (t < 10) {
        float m = -1e30f;
        #pragma unroll
        for (int j = 0; j < 10; j++) m = fmaxf(m, lg[j]);
        float sum = 0.0f;
        #pragma unroll
        for (int j = 0; j < 10; j++) sum += expf(lg[j] - m);
        out[row * 10 + t] = lg[t] - m - logf(sum);
    }
}

extern "C" void kernel_launch(void* const* d_in, const int* in_sizes, int n_in,
                              void* d_out, int out_size, void* d_ws, size_t ws_size,
                              hipStream_t stream) {
    const float* x0      = (const float*)d_in[0];
    const int*   cluster0= (const int*)d_in[1];
    const int*   edge1   = (const int*)d_in[2];
    const float* pseudo1 = (const float*)d_in[3];
    const float* W1      = (const float*)d_in[4];
    const float* root1   = (const float*)d_in[5];
    const float* b1      = (const float*)d_in[6];
    const int*   cluster1= (const int*)d_in[7];
    const int*   edge2   = (const int*)d_in[8];
    const float* pseudo2 = (const float*)d_in[9];
    const float* W2      = (const float*)d_in[10];
    const float* root2   = (const float*)d_in[11];
    const float* b2      = (const float*)d_in[12];
    const int*   cluster2= (const int*)d_in[13];
    const int*   edge3   = (const int*)d_in[14];
    const float* pseudo3 = (const float*)d_in[15];
    const float* W3      = (const float*)d_in[16];
    const float* root3   = (const float*)d_in[17];
    const float* b3      = (const float*)d_in[18];
    const int*   cluster3= (const int*)d_in[19];
    const float* fc1_w   = (const float*)d_in[20];
    const float* fc1_b   = (const float*)d_in[21];
    const float* fc2_w   = (const float*)d_in[22];
    const float* fc2_b   = (const float*)d_in[23];
    float* out = (float*)d_out;

    float* ws = (float*)d_ws;
    size_t off = 0;
    float* xm1  = ws + off; off += 20480;
    float* x1   = ws + off; off += (size_t)N1c * 64;
    float* agg1 = ws + off; off += (size_t)N1c * 64;
    float* deg1 = ws + off; off += 20480;
    float* xm2  = ws + off; off += (size_t)N2c * 64;
    float* x2   = ws + off; off += (size_t)N2c * 64;
    float* agg2 = ws + off; off += (size_t)N2c * 64;
    float* deg2 = ws + off; off += 6144;
    float* xm3  = ws + off; off += (size_t)N3c * 64;
    float* x3   = ws + off; off += (size_t)N3c * 128;
    float* agg3 = ws + off; off += (size_t)N3c * 128;
    float* deg3 = ws + off; off += 2048;
    float* xm4  = ws + off; off += 512 * 128;
    float* h1   = ws + off; off += 64 * 256;

    hipMemsetAsync(d_ws, 0, off * sizeof(float), stream);

    // pool 0: x0 -> xm1 (N1 x 1)
    segmax_scatter<<<(N0c + 255) / 256, 256, 0, stream>>>(x0, cluster0, (unsigned*)xm1, N0c, 0);
    segmax_decode<<<(N1c + 255) / 256, 256, 0, stream>>>((unsigned*)xm1, N1c);

    // conv1 (1 -> 64) on N1 nodes, E1 edges
    conv1_edge<<<(E1c * 64) / 256, 256, 0, stream>>>(edge1, pseudo1, W1, xm1, agg1, deg1);
    node1<<<(N1c * 64) / 256, 256, 0, stream>>>(agg1, deg1, xm1, root1, b1, x1, N1c);

    // pool 1: x1 -> xm2 (N2 x 64)
    segmax_scatter<<<(N1c * 64) / 256, 256, 0, stream>>>(x1, cluster1, (unsigned*)xm2, N1c * 64, 6);
    segmax_decode<<<(N2c * 64) / 256, 256, 0, stream>>>((unsigned*)xm2, N2c * 64);

    // conv2 (64 -> 64) on N2 nodes, E2 edges
    conv2_edge<<<(E2c + 3) / 4, 256, 0, stream>>>(edge2, pseudo2, W2, xm2, agg2, deg2, E2c);
    node_mm<64><<<(N2c * 64) / 256, 256, 0, stream>>>(agg2, deg2, xm2, root2, b2, x2, N2c);

    // pool 2: x2 -> xm3 (N3 x 64)
    segmax_scatter<<<(N2c * 64) / 256, 256, 0, stream>>>(x2, cluster2, (unsigned*)xm3, N2c * 64, 6);
    segmax_decode<<<(N3c * 64) / 256, 256, 0, stream>>>((unsigned*)xm3, N3c * 64);

    // conv3 (64 -> 128) on N3 nodes, E3 edges
    conv3_edge<<<(E3c + 3) / 4, 256, 0, stream>>>(edge3, pseudo3, W3, xm3, agg3, deg3, E3c);
    node_mm<128><<<(N3c * 128) / 256, 256, 0, stream>>>(agg3, deg3, xm3, root3, b3, x3, N3c);

    // pool 3: x3 -> xm4 (512 x 128) == (64 x 1024)
    segmax_scatter<<<(N3c * 128) / 256, 256, 0, stream>>>(x3, cluster3, (unsigned*)xm4, N3c * 128, 7);
    segmax_decode<<<(512 * 128) / 256, 256, 0, stream>>>((unsigned*)xm4, 512 * 128);

    // FC head
    fc1_k<<<64, 256, 0, stream>>>(xm4, fc1_w, fc1_b, h1);
    fc2_k<<<64, 64, 0, stream>>>(h1, fc2_w, fc2_b, out);
}